// Round 1
// baseline (388.444 us; speedup 1.0000x reference)
//
#include <hip/hip_runtime.h>
#include <stdint.h>
#include <string.h>

#define N_USER 50000
#define N_ITEM 50000
#define N_EDGE 600000
#define D 128
#define NTOT 150000      // 3 * 50000 destination slots (uu | ub | iu)
#define ETOT 1800000
#define NB 147           // buckets = ceil(NTOT / SPAN)
#define BSH 10
#define SPAN 1024        // slots per bucket
#define CHUNK 4096       // edges per block in bucket kernels (16/thread)

typedef unsigned short u16;
typedef unsigned int   u32;
typedef __attribute__((ext_vector_type(8))) short short8;   // 8 bf16 (MFMA A/B frag)
typedef __attribute__((ext_vector_type(4))) float floatx4;  // MFMA C/D frag

static __device__ __forceinline__ u16 f2b(float f) {        // f32 -> bf16 RNE
  u32 x; memcpy(&x, &f, 4);
  u32 r = x + 0x7fffu + ((x >> 16) & 1u);
  return (u16)(r >> 16);
}
static __device__ __forceinline__ float blo2f(u32 v) {
  u32 x = v << 16; float f; memcpy(&f, &x, 4); return f;
}
static __device__ __forceinline__ float bhi2f(u32 v) {
  u32 x = v & 0xffff0000u; float f; memcpy(&f, &x, 4); return f;
}

// ---- prep: blocks 0-2 transpose+bf16 the weights; rest convert fu AND fi to bf16 ----
__global__ void k_prep(const float* __restrict__ W0, const float* __restrict__ W1,
                       const float* __restrict__ W2, u16* __restrict__ WT,
                       const float* __restrict__ fu, const float* __restrict__ fi,
                       u16* __restrict__ fb_u, u16* __restrict__ fb_i) {
  int bid = blockIdx.x;
  if (bid < 3) {
    const float* W = (bid == 0) ? W0 : ((bid == 1) ? W1 : W2);
    u16* T = WT + bid * D * D;
    for (int idx = threadIdx.x; idx < D * D; idx += blockDim.x) {
      int n = idx >> 7, k = idx & 127;
      T[idx] = f2b(W[k * D + n]);
    }
  } else {
    int g = bid - 3;
    const float* src = fu; u16* dst = fb_u;
    if (g >= 6250) { g -= 6250; src = fi; dst = fb_i; }
    int gid = g * 256 + threadIdx.x;    // float4 groups: 1.6M per tensor
    float4 v = ((const float4*)src)[gid];
    union { u16 u[4]; uint2 d; } pk;
    pk.u[0] = f2b(v.x); pk.u[1] = f2b(v.y); pk.u[2] = f2b(v.z); pk.u[3] = f2b(v.w);
    ((uint2*)dst)[gid] = pk.d;
  }
}

// ---- bucket histogram: LDS-staged, 147 coarse global atomics per block ----
__global__ void __launch_bounds__(256) k_bhist(const int* __restrict__ duu, const int* __restrict__ dub,
                                               const int* __restrict__ diu, int* __restrict__ bhist) {
  __shared__ int h[NB];
  for (int i = threadIdx.x; i < NB; i += 256) h[i] = 0;
  __syncthreads();
  int base = blockIdx.x * CHUNK;
  for (int j = threadIdx.x; j < CHUNK; j += 256) {
    int e = base + j;
    if (e < ETOT) {
      int t = e / N_EDGE, i = e - t * N_EDGE;
      int d = (t == 0) ? duu[i] : ((t == 1) ? dub[i] : diu[i]);
      atomicAdd(&h[(t * N_USER + d) >> BSH], 1);
    }
  }
  __syncthreads();
  for (int i = threadIdx.x; i < NB; i += 256) if (h[i]) atomicAdd(&bhist[i], h[i]);
}

// ---- exclusive scan of 147 bucket totals (1 block) ----
__global__ void k_bscan(const int* __restrict__ bhist, int* __restrict__ boff) {
  __shared__ int buf[256];
  int t = threadIdx.x;
  int v = (t < NB) ? bhist[t] : 0;
  buf[t] = v; __syncthreads();
  for (int s = 1; s < 256; s <<= 1) {
    int y = (t >= s) ? buf[t - s] : 0;
    __syncthreads(); buf[t] += y; __syncthreads();
  }
  if (t <= NB) boff[t] = (t == 0) ? 0 : buf[t - 1];
}

// ---- place edges into bucket-grouped ebuf: payload = src | (slot&1023)<<16 ----
__global__ void __launch_bounds__(256) k_bplace(
    const int* __restrict__ suu, const int* __restrict__ duu,
    const int* __restrict__ sub, const int* __restrict__ dub,
    const int* __restrict__ siu, const int* __restrict__ diu,
    const int* __restrict__ boff, int* __restrict__ cursor, u32* __restrict__ ebuf) {
  __shared__ int h[NB];
  for (int i = threadIdx.x; i < NB; i += 256) h[i] = 0;
  __syncthreads();
  int base = blockIdx.x * CHUNK;
  u32 pay[16], br[16];
#pragma unroll
  for (int k = 0; k < 16; ++k) {
    int e = base + k * 256 + threadIdx.x;
    br[k] = 0xFFFFFFFFu;
    if (e < ETOT) {
      int t = e / N_EDGE, i = e - t * N_EDGE;
      int d, s;
      if (t == 0)      { d = duu[i]; s = suu[i]; }
      else if (t == 1) { d = dub[i]; s = sub[i]; }
      else             { d = diu[i]; s = siu[i]; }
      int slot = t * N_USER + d;
      int bu = slot >> BSH;
      int rank = atomicAdd(&h[bu], 1);
      pay[k] = (u32)s | ((u32)(slot & (SPAN - 1)) << 16);
      br[k]  = (u32)bu | ((u32)rank << 8);       // bu<=146 fits 8 bits; rank<4096
    }
  }
  __syncthreads();
  for (int i = threadIdx.x; i < NB; i += 256)
    h[i] = boff[i] + atomicAdd(&cursor[i], h[i]);    // block's base within bucket region
  __syncthreads();
#pragma unroll
  for (int k = 0; k < 16; ++k) {
    if (br[k] != 0xFFFFFFFFu) {
      int bu = br[k] & 0xFF, rank = (int)(br[k] >> 8);
      ebuf[h[bu] + rank] = pay[k];
    }
  }
}

// ---- per-bucket CSR finalize: off[] (coalesced) + ssrc[] (L2-local scatter) ----
__global__ void __launch_bounds__(256) k_csr(const int* __restrict__ boff, const u32* __restrict__ ebuf,
                                             int* __restrict__ off, u16* __restrict__ ssrc) {
  __shared__ int sc[SPAN];
  __shared__ int so[SPAN];
  __shared__ int part[256];
  int b = blockIdx.x;
  int ebase = boff[b], ecnt = boff[b + 1] - ebase;
  int sbase = b << BSH;
  int nslots = (NTOT - sbase < SPAN) ? (NTOT - sbase) : SPAN;
  for (int i = threadIdx.x; i < SPAN; i += 256) sc[i] = 0;
  __syncthreads();
  for (int j = threadIdx.x; j < ecnt; j += 256)
    atomicAdd(&sc[ebuf[ebase + j] >> 16], 1);
  __syncthreads();
  int t = threadIdx.x;
  int s0 = sc[4*t], s1 = sc[4*t+1], s2 = sc[4*t+2], s3 = sc[4*t+3];
  int tsum = s0 + s1 + s2 + s3;
  part[t] = tsum; __syncthreads();
  for (int s = 1; s < 256; s <<= 1) {
    int y = (t >= s) ? part[t - s] : 0;
    __syncthreads(); part[t] += y; __syncthreads();
  }
  int pbase = part[t] - tsum;
  so[4*t]   = pbase;
  so[4*t+1] = pbase + s0;
  so[4*t+2] = pbase + s0 + s1;
  so[4*t+3] = pbase + s0 + s1 + s2;
  __syncthreads();
  for (int i = threadIdx.x; i < nslots; i += 256)
    off[sbase + i] = ebase + so[i];
  if (b == 0 && threadIdx.x == 0) off[NTOT] = ETOT;
  for (int i = threadIdx.x; i < SPAN; i += 256) sc[i] = so[i];   // cursors
  __syncthreads();
  for (int j = threadIdx.x; j < ecnt; j += 256) {
    u32 p = ebuf[ebase + j];
    int pos = atomicAdd(&sc[p >> 16], 1);
    ssrc[ebase + pos] = (u16)(p & 0xFFFFu);
  }
}

// ---- gather-mean per (type,dst), one wave per slot; all-bf16 gather + bf16 mean out ----
__global__ void __launch_bounds__(256) k_mean(const u16* __restrict__ fb_u, const u16* __restrict__ fb_i,
                                              const int* __restrict__ off, const u16* __restrict__ ssrc,
                                              u16* __restrict__ mean_uu, u16* __restrict__ mean_ub,
                                              u16* __restrict__ mean_iu) {
  int slot = blockIdx.x * 4 + (threadIdx.x >> 6);
  int lane = threadIdx.x & 63;
  if (slot >= NTOT) return;
  int t = slot / N_USER;
  int d = slot - t * N_USER;
  const u16* fb = (t == 2) ? fb_i : fb_u;
  int s = off[slot], e = off[slot + 1];
  float a0 = 0.f, a1 = 0.f;
  int i = s;
  for (; i + 4 <= e; i += 4) {
    int s0 = ssrc[i], s1 = ssrc[i + 1], s2 = ssrc[i + 2], s3 = ssrc[i + 3];
    u32 v0 = ((const u32*)(fb + (size_t)s0 * D))[lane];
    u32 v1 = ((const u32*)(fb + (size_t)s1 * D))[lane];
    u32 v2 = ((const u32*)(fb + (size_t)s2 * D))[lane];
    u32 v3 = ((const u32*)(fb + (size_t)s3 * D))[lane];
    a0 += blo2f(v0) + blo2f(v1) + blo2f(v2) + blo2f(v3);
    a1 += bhi2f(v0) + bhi2f(v1) + bhi2f(v2) + bhi2f(v3);
  }
  for (; i < e; ++i) {
    u32 v = ((const u32*)(fb + (size_t)ssrc[i] * D))[lane];
    a0 += blo2f(v); a1 += bhi2f(v);
  }
  int n = e - s;
  float inv = (n > 0) ? 1.0f / (float)n : 0.f;
  u16* md = (t == 0) ? mean_uu : ((t == 1) ? mean_ub : mean_iu);
  u32 pk = (u32)f2b(a0 * inv) | ((u32)f2b(a1 * inv) << 16);
  ((u32*)(md + (size_t)d * D))[lane] = pk;
}

// ---- final GEMM: bf16 A (means) x bf16 W^T -> f32 out; self-calibrating C/D layout ----
// Launched twice: user pass (A0=mean_uu@W0 + A1=mean_iu@W1), then item pass (A0=mean_ub@W0).
__global__ void __launch_bounds__(256) k_out(const u16* __restrict__ A0, const u16* __restrict__ A1,
                                             const u16* __restrict__ W0, const u16* __restrict__ W1,
                                             const float* __restrict__ b0, const float* __restrict__ b1,
                                             const int* __restrict__ off, int ob0, int ob1,
                                             float* __restrict__ op) {
  int tid = threadIdx.x;
  int w = tid >> 6, lane = tid & 63, quad = lane >> 4, l16 = lane & 15;
  int row_base = blockIdx.x * 64;
  int r0 = row_base + w * 16 + l16;
  int rA = r0 < N_USER ? r0 : N_USER - 1;

  // calibration MFMA: recover (row,col) mapping of C/D fragment registers
  short8 apb, bpb;
#pragma unroll
  for (int j = 0; j < 8; j++) {
    int k = quad * 8 + j;
    apb[j] = (short)((k == l16) ? 0x3F80 : 0);
    bpb[j] = (short)((k < 16) ? f2b((float)(k * 16 + l16)) : 0);
  }
  floatx4 pz = (floatx4){0.f, 0.f, 0.f, 0.f};
  floatx4 pr = __builtin_amdgcn_mfma_f32_16x16x32_bf16(apb, bpb, pz, 0, 0, 0);
  int rowm[4], colm[4];
#pragma unroll
  for (int i = 0; i < 4; i++) { int v = (int)pr[i]; rowm[i] = v >> 4; colm[i] = v & 15; }

  floatx4 acc[8];
#pragma unroll
  for (int i = 0; i < 8; i++) acc[i] = (floatx4){0.f, 0.f, 0.f, 0.f};

  {
    const short8* aptr = (const short8*)(A0 + (size_t)rA * D + quad * 8);
#pragma unroll
    for (int kk = 0; kk < 4; ++kk) {
      short8 af = aptr[kk * 4];
      const short8* bptr = (const short8*)(W0 + l16 * D + kk * 32 + quad * 8);
#pragma unroll
      for (int nt = 0; nt < 8; ++nt)
        acc[nt] = __builtin_amdgcn_mfma_f32_16x16x32_bf16(af, bptr[nt * 256], acc[nt], 0, 0, 0);
    }
  }
  if (A1) {
    const short8* aptr = (const short8*)(A1 + (size_t)rA * D + quad * 8);
#pragma unroll
    for (int kk = 0; kk < 4; ++kk) {
      short8 af = aptr[kk * 4];
      const short8* bptr = (const short8*)(W1 + l16 * D + kk * 32 + quad * 8);
#pragma unroll
      for (int nt = 0; nt < 8; ++nt)
        acc[nt] = __builtin_amdgcn_mfma_f32_16x16x32_bf16(af, bptr[nt * 256], acc[nt], 0, 0, 0);
    }
  }

  __shared__ float lds[64 * 132];
#pragma unroll
  for (int nt = 0; nt < 8; ++nt)
#pragma unroll
    for (int r = 0; r < 4; ++r)
      lds[(w * 16 + rowm[r]) * 132 + nt * 16 + colm[r]] = acc[nt][r];
  __syncthreads();

#pragma unroll
  for (int i = 0; i < 4; i++) {
    int linear = tid + i * 256;
    int row = linear >> 4;
    int cg  = (linear & 15) * 8;
    int grow = row_base + row;
    if (grow < N_USER) {
      int n0 = off[ob0 + grow + 1] - off[ob0 + grow];
      int n1 = A1 ? (off[ob1 + grow + 1] - off[ob1 + grow]) : 0;
      float res[8];
#pragma unroll
      for (int j = 0; j < 8; j++) {
        float b = (n0 > 0 ? b0[cg + j] : 0.f) + ((A1 && n1 > 0) ? b1[cg + j] : 0.f);
        res[j] = lds[row * 132 + cg + j] + b;
      }
      float4* dst = (float4*)(op + (size_t)grow * D + cg);
      dst[0] = make_float4(res[0], res[1], res[2], res[3]);
      dst[1] = make_float4(res[4], res[5], res[6], res[7]);
    }
  }
}

extern "C" void kernel_launch(void* const* d_in, const int* in_sizes, int n_in,
                              void* d_out, int out_size, void* d_ws, size_t ws_size,
                              hipStream_t stream) {
  const float* fu  = (const float*)d_in[0];
  const float* fi  = (const float*)d_in[1];
  const float* Wuu = (const float*)d_in[2];
  const float* buu = (const float*)d_in[3];
  const float* Wub = (const float*)d_in[4];
  const float* bub = (const float*)d_in[5];
  const float* Wiu = (const float*)d_in[6];
  const float* biu = (const float*)d_in[7];
  const int* suu = (const int*)d_in[8];
  const int* duu = (const int*)d_in[9];
  const int* sub = (const int*)d_in[10];
  const int* dub = (const int*)d_in[11];
  const int* siu = (const int*)d_in[12];
  const int* diu = (const int*)d_in[13];
  float* out = (float*)d_out;   // f32: [out_user 50000x128 | out_item 50000x128]

  // ---- d_out doubles as scratch (race-free schedule; every byte rewritten) ----
  // bytes [0.0,12.8M): fb_u  bf16   (prep -> mean, dead before k_out#1 writes)
  // bytes [12.8,25.6M): fb_i bf16   (prep -> mean, dead before k_out#1 writes)
  // bytes [25.6,38.4M): mean_uu bf16 (mean -> k_out#1 read; k_out#2 overwrites after)
  // bytes [38.4,51.2M): mean_iu bf16 (mean -> k_out#1 read; k_out#2 overwrites after)
  u16* ob      = (u16*)d_out;
  u16* fb_u    = ob;
  u16* fb_i    = ob + 6400000;
  u16* mean_uu = ob + 12800000;
  u16* mean_iu = ob + 19200000;

  // workspace layout (24.3 MB)
  int* wsi    = (int*)d_ws;
  int* off    = wsi;                        // [150001]
  int* bhist  = wsi + 150016;               // [147]
  int* cursor = wsi + 150208;               // [147]
  int* boff   = wsi + 150400;               // [148]
  u32* ebuf   = (u32*)(wsi + 150592);       // [1800000] (7.2 MB)
  u16* ssrc   = (u16*)(wsi + 1950592);      // [1800000] u16 (3.6 MB)
  u16* WT     = (u16*)(wsi + 2850592);      // 3*128*128 bf16, 16B-aligned
  u16* mean_ub= (u16*)(wsi + 2875168);      // 50000*128 bf16 (12.8 MB)

  const int NBLK = (ETOT + CHUNK - 1) / CHUNK;   // 440

  hipMemsetAsync(bhist, 0, 384 * sizeof(int), stream);   // bhist + cursor
  k_prep<<<3 + 12500, 256, 0, stream>>>(Wuu, Wub, Wiu, WT, fu, fi, fb_u, fb_i);
  k_bhist<<<NBLK, 256, 0, stream>>>(duu, dub, diu, bhist);
  k_bscan<<<1, 256, 0, stream>>>(bhist, boff);
  k_bplace<<<NBLK, 256, 0, stream>>>(suu, duu, sub, dub, siu, diu, boff, cursor, ebuf);
  k_csr<<<NB, 256, 0, stream>>>(boff, ebuf, off, ssrc);
  k_mean<<<37500, 256, 0, stream>>>(fb_u, fb_i, off, ssrc, mean_uu, mean_ub, mean_iu);
  // user pass: reads [25.6,51.2M), writes [0,25.6M)  -- disjoint
  k_out<<<782, 256, 0, stream>>>(mean_uu, mean_iu, WT, WT + 2 * D * D,
                                 buu, biu, off, 0, 2 * N_USER, out);
  // item pass: reads ws mean_ub, writes [25.6,51.2M) -- after user pass (stream order)
  k_out<<<782, 256, 0, stream>>>(mean_ub, (const u16*)nullptr, WT + D * D, (const u16*)nullptr,
                                 bub, (const float*)nullptr, off, N_USER, 0,
                                 out + (size_t)N_USER * D);
}